// Round 4
// baseline (33.976 us; speedup 1.0000x reference)
//
#include <hip/hip_runtime.h>
#include <math.h>

#define DIM  4096
#define KOUT 10
#define BATCH 4096

// XOR-swizzle on linear LDS float index (R1-verbatim).
__device__ __forceinline__ int swzAddr(int lin) {
    return lin ^ (((lin >> 6) & 7) << 2);
}

__device__ __forceinline__ float rlane(float v, int lane) {
    return __int_as_float(__builtin_amdgcn_readlane(__float_as_int(v), lane));
}

// One RY layer on reg-bit K via 3-fma lifting shears.
// Caller passes t = tan(phi/2), s = sin(phi) for rotation angle phi
// (or t = -cot(phi/2), s = -sin(phi) => -R(phi); sign cancels in probs).
// Result per pair: r[i0] = cos(phi)*a - sin(phi)*b ; r[i1] = sin(phi)*a + cos(phi)*b
template<int K>
__device__ __forceinline__ void liftLayer(float r[64], float t, float s) {
#pragma unroll
    for (int m = 0; m < 32; ++m) {
        const int i0 = ((m >> K) << (K + 1)) | (m & ((1 << K) - 1));
        const int i1 = i0 | (1 << K);
        float a = r[i0], b = r[i1];
        float a1 = fmaf(-t, b, a);
        float b1 = fmaf(s, a1, b);
        r[i1] = b1;
        r[i0] = fmaf(-t, b1, a1);
    }
}

// R1-verbatim: read 64 floats r[j] = lds_logical[l*64 + j] via swizzled b128
__device__ __forceinline__ void ldsRead64(const float* lds, int l, float r[64]) {
#pragma unroll
    for (int e4 = 0; e4 < 16; ++e4) {
        const float4 w = *reinterpret_cast<const float4*>(&lds[swzAddr(l * 64 + e4 * 4)]);
        r[e4 * 4 + 0] = w.x; r[e4 * 4 + 1] = w.y;
        r[e4 * 4 + 2] = w.z; r[e4 * 4 + 3] = w.w;
    }
}

// R1-verbatim: transposed write, element at local j -> linear j*64 + l
__device__ __forceinline__ void ldsWriteT(float* lds, int l, const float r[64]) {
#pragma unroll
    for (int j = 0; j < 64; ++j)
        lds[swzAddr(j * 64 + l)] = r[j];
}

__global__ __launch_bounds__(64) void vqc_kernel(
        const float* __restrict__ x,
        const float* __restrict__ theta,
        float* __restrict__ out)
{
    __shared__ __align__(16) float lds[DIM];   // 16 KB
    const int l = threadIdx.x;   // one wave per block, one batch row per block
    const int b = blockIdx.x;

    // Gate params for lifting. RY(theta) rotates by phi = theta/2:
    // t = tan(theta/4), s = sin(theta/2); alt branch -R(phi) keeps |t|<=1.
    float th = theta[l < 24 ? l : 0];
    float qh = 0.25f * th;
    float sq = sinf(qh), cq = cosf(qh);
    float sfull = 2.f * sq * cq;                       // sin(theta/2)
    float tt, ss;
    if (fabsf(sq) <= fabsf(cq)) { tt = sq / cq;  ss = sfull;  }
    else                        { tt = -cq / sq; ss = -sfull; }

    // ---- direct load into pass-1 layout: r[j] = x[b*DIM + l*64 + j] ----
    float r[64];
    const float4* x4 = reinterpret_cast<const float4*>(x + (size_t)b * DIM + l * 64);
#pragma unroll
    for (int e4 = 0; e4 < 16; ++e4) {
        const float4 w = x4[e4];
        r[e4 * 4 + 0] = w.x; r[e4 * 4 + 1] = w.y;
        r[e4 * 4 + 2] = w.z; r[e4 * 4 + 3] = w.w;
    }

    // ---- pass 1: qubits 0-5, layer 1 (thread l holds d = l*64 + j) ----
    liftLayer<0>(r, rlane(tt, 0), rlane(ss, 0));
    liftLayer<1>(r, rlane(tt, 1), rlane(ss, 1));
    liftLayer<2>(r, rlane(tt, 2), rlane(ss, 2));
    liftLayer<3>(r, rlane(tt, 3), rlane(ss, 3));
    liftLayer<4>(r, rlane(tt, 4), rlane(ss, 4));
    liftLayer<5>(r, rlane(tt, 5), rlane(ss, 5));
    ldsWriteT(lds, l, r);                    // -> transposed layout
    ldsRead64(lds, l, r);                    // r[j] = state[(j<<6)|l]

    // ---- pass 2: qubits 6-11, layer 1 ----
    liftLayer<0>(r, rlane(tt, 6),  rlane(ss, 6));
    liftLayer<1>(r, rlane(tt, 7),  rlane(ss, 7));
    liftLayer<2>(r, rlane(tt, 8),  rlane(ss, 8));
    liftLayer<3>(r, rlane(tt, 9),  rlane(ss, 9));
    liftLayer<4>(r, rlane(tt, 10), rlane(ss, 10));
    liftLayer<5>(r, rlane(tt, 11), rlane(ss, 11));

    // CZ diagonal (R1-verbatim): lane bits = qubits 0-5, reg bits e = qubits 6-11
    {
        int f  = __popc(l & (l >> 1) & 0x1F) & 1;  // pairs among qubits 0-5
        int l5 = (l >> 5) & 1, l0 = l & 1;
        float sg0 = f              ? -1.f : 1.f;
        float sg1 = (f ^ l5)       ? -1.f : 1.f;   // e0=1: pair (5,6)
        float sg2 = (f ^ l0)       ? -1.f : 1.f;   // e5=1: pair (0,11)
        float sg3 = (f ^ l5 ^ l0)  ? -1.f : 1.f;
#pragma unroll
        for (int e = 0; e < 64; ++e) {
            const int Ce  = __popc(e & (e >> 1) & 0x1F) & 1;  // pairs among qubits 6-11
            const int sel = (e & 1) | (((e >> 5) & 1) << 1);
            float sgn;
            if      (sel == 0) sgn = sg0;
            else if (sel == 1) sgn = sg1;
            else if (sel == 2) sgn = sg2;
            else               sgn = sg3;
            r[e] *= (Ce ? -sgn : sgn);
        }
    }

    // ---- layer 2 on qubits 6-11 (theta[18..23]) ----
    liftLayer<0>(r, rlane(tt, 18), rlane(ss, 18));
    liftLayer<1>(r, rlane(tt, 19), rlane(ss, 19));
    liftLayer<2>(r, rlane(tt, 20), rlane(ss, 20));
    liftLayer<3>(r, rlane(tt, 21), rlane(ss, 21));
    liftLayer<4>(r, rlane(tt, 22), rlane(ss, 22));
    liftLayer<5>(r, rlane(tt, 23), rlane(ss, 23));
    ldsWriteT(lds, l, r);                    // transpose back
    ldsRead64(lds, l, r);                    // r[j] = state[l*64 + j]

    // ---- pass 3: qubits 0-5, layer 2 (theta[12..17]) ----
    liftLayer<0>(r, rlane(tt, 12), rlane(ss, 12));
    liftLayer<1>(r, rlane(tt, 13), rlane(ss, 13));
    liftLayer<2>(r, rlane(tt, 14), rlane(ss, 14));
    liftLayer<3>(r, rlane(tt, 15), rlane(ss, 15));
    liftLayer<4>(r, rlane(tt, 16), rlane(ss, 16));
    liftLayer<5>(r, rlane(tt, 17), rlane(ss, 17));

    // ---- measurement (R1-verbatim): bits 0-5 of d = j, bits 6-9 = l&15 ----
    float psum = 0.f;
#pragma unroll
    for (int j = 0; j < 64; ++j) psum = fmaf(r[j], r[j], psum);

    float v[10];
#pragma unroll
    for (int k = 0; k < 6; ++k) {
        float mk = 0.f;
#pragma unroll
        for (int j = 0; j < 64; ++j)
            if (j & (1 << k)) mk = fmaf(r[j], r[j], mk);
        v[k] = mk;
    }
    v[6] = (l & 1) ? psum : 0.f;
    v[7] = (l & 2) ? psum : 0.f;
    v[8] = (l & 4) ? psum : 0.f;
    v[9] = (l & 8) ? psum : 0.f;

#pragma unroll
    for (int k = 0; k < 10; ++k) {
        float t = v[k];
#pragma unroll
        for (int off = 32; off >= 1; off >>= 1)
            t += __shfl_xor(t, off, 64);
        v[k] = t;
    }

    if (l == 0) {
#pragma unroll
        for (int k = 0; k < KOUT; ++k) out[b * KOUT + k] = v[k];
    }
}

extern "C" void kernel_launch(void* const* d_in, const int* in_sizes, int n_in,
                              void* d_out, int out_size, void* d_ws, size_t ws_size,
                              hipStream_t stream) {
    const float* x     = (const float*)d_in[0];
    const float* theta = (const float*)d_in[1];
    float* out         = (float*)d_out;
    vqc_kernel<<<BATCH, 64, 0, stream>>>(x, theta, out);
}

// Round 6
// 29.116 us; speedup vs baseline: 1.1669x; 1.1669x over previous
//
#include <hip/hip_runtime.h>
#include <math.h>

#define DIM  4096
#define KOUT 10
#define BATCH 4096

// XOR-swizzle on linear LDS float index (verified in R1/R4): XOR row bits
// (6-8) into 16B-granule slot bits (2-4). Involution; row-contiguous b128
// accesses and strided-64 b32 accesses both land at the bank floor.
__device__ __forceinline__ int swzAddr(int lin) {
    return lin ^ (((lin >> 6) & 7) << 2);
}

__device__ __forceinline__ float rlane(float v, int lane) {
    return __int_as_float(__builtin_amdgcn_readlane(__float_as_int(v), lane));
}

// Drain all pending LDS ops. Needed before overwriting LDS rows that a
// prior same-wave ds_read has read but possibly not yet returned (WAR):
// the compiler only inserts lgkmcnt waits before USES of loaded data,
// never before subsequent ds_writes. sched_barrier on both sides keeps
// the compiler from moving DS ops across the fence (guide rule #18).
__device__ __forceinline__ void ldsFence() {
    __builtin_amdgcn_sched_barrier(0);
    asm volatile("s_waitcnt lgkmcnt(0)" ::: "memory");
    __builtin_amdgcn_sched_barrier(0);
}

// One RY layer on reg-bit K via 3-fma lifting shears (verified in R4).
// t = tan(phi/2), s = sin(phi) for rotation angle phi (or -cot/-sin => -R).
template<int K>
__device__ __forceinline__ void liftLayer(float r[64], float t, float s) {
#pragma unroll
    for (int m = 0; m < 32; ++m) {
        const int i0 = ((m >> K) << (K + 1)) | (m & ((1 << K) - 1));
        const int i1 = i0 | (1 << K);
        float a = r[i0], b = r[i1];
        float a1 = fmaf(-t, b, a);
        float b1 = fmaf(s, a1, b);
        r[i1] = b1;
        r[i0] = fmaf(-t, b1, a1);
    }
}

// 8 KB time-shared lane<->reg transpose: r_new[j]@lane l = r_old[l]@lane j.
// Phase 0: source lanes 0..31 write their 64 regs as row l (b128, swizzled);
// all lanes read column l of rows 0..31 into tmp. Phase 1: lanes 32..63
// write rows 0..31; all lanes read into r[32..63]. WAR fences before each
// write block guarantee prior reads have returned before the overwrite.
__device__ __forceinline__ void transpose64(float r[64], float* lds, int l) {
    float tmp[32];
    ldsFence();                 // vs. previous transpose's phase-1 reads
    if (l < 32) {
#pragma unroll
        for (int e4 = 0; e4 < 16; ++e4)
            *reinterpret_cast<float4*>(&lds[swzAddr(l * 64 + e4 * 4)]) =
                make_float4(r[e4 * 4 + 0], r[e4 * 4 + 1],
                            r[e4 * 4 + 2], r[e4 * 4 + 3]);
    }
#pragma unroll
    for (int j = 0; j < 32; ++j)
        tmp[j] = lds[swzAddr(j * 64 + l)];          // = r_old[l]@lane j, j<32
    ldsFence();                 // vs. phase-0 reads just issued
    if (l >= 32) {
#pragma unroll
        for (int e4 = 0; e4 < 16; ++e4)
            *reinterpret_cast<float4*>(&lds[swzAddr((l - 32) * 64 + e4 * 4)]) =
                make_float4(r[e4 * 4 + 0], r[e4 * 4 + 1],
                            r[e4 * 4 + 2], r[e4 * 4 + 3]);
    }
#pragma unroll
    for (int j = 0; j < 32; ++j)
        r[32 + j] = lds[swzAddr(j * 64 + l)];       // = r_old[l]@lane 32+j
#pragma unroll
    for (int j = 0; j < 32; ++j)
        r[j] = tmp[j];
}

__global__ __launch_bounds__(64) void vqc_kernel(
        const float* __restrict__ x,
        const float* __restrict__ theta,
        float* __restrict__ out)
{
    __shared__ __align__(16) float lds[2048];   // 8 KB
    const int l = threadIdx.x;   // one wave per block, one batch row per block
    const int b = blockIdx.x;

    // Gate params for lifting. RY(theta) rotates by phi = theta/2:
    // t = tan(theta/4), s = sin(theta/2); alt branch -R(phi) keeps |t|<=1.
    float th = theta[l < 24 ? l : 0];
    float qh = 0.25f * th;
    float sq = sinf(qh), cq = cosf(qh);
    float sfull = 2.f * sq * cq;                       // sin(theta/2)
    float tt, ss;
    if (fabsf(sq) <= fabsf(cq)) { tt = sq / cq;  ss = sfull;  }
    else                        { tt = -cq / sq; ss = -sfull; }

    // ---- direct load into pass-1 layout: r[j] = x[b*DIM + l*64 + j] ----
    float r[64];
    const float4* x4 = reinterpret_cast<const float4*>(x + (size_t)b * DIM + l * 64);
#pragma unroll
    for (int e4 = 0; e4 < 16; ++e4) {
        const float4 w = x4[e4];
        r[e4 * 4 + 0] = w.x; r[e4 * 4 + 1] = w.y;
        r[e4 * 4 + 2] = w.z; r[e4 * 4 + 3] = w.w;
    }

    // ---- pass 1: qubits 0-5, layer 1 (thread l holds d = l*64 + j) ----
    liftLayer<0>(r, rlane(tt, 0), rlane(ss, 0));
    liftLayer<1>(r, rlane(tt, 1), rlane(ss, 1));
    liftLayer<2>(r, rlane(tt, 2), rlane(ss, 2));
    liftLayer<3>(r, rlane(tt, 3), rlane(ss, 3));
    liftLayer<4>(r, rlane(tt, 4), rlane(ss, 4));
    liftLayer<5>(r, rlane(tt, 5), rlane(ss, 5));

    transpose64(r, lds, l);                  // r[j] = state[(j<<6)|l]

    // ---- pass 2: qubits 6-11, layer 1 ----
    liftLayer<0>(r, rlane(tt, 6),  rlane(ss, 6));
    liftLayer<1>(r, rlane(tt, 7),  rlane(ss, 7));
    liftLayer<2>(r, rlane(tt, 8),  rlane(ss, 8));
    liftLayer<3>(r, rlane(tt, 9),  rlane(ss, 9));
    liftLayer<4>(r, rlane(tt, 10), rlane(ss, 10));
    liftLayer<5>(r, rlane(tt, 11), rlane(ss, 11));

    // CZ diagonal (verified): lane bits = qubits 0-5, reg bits e = qubits 6-11
    {
        int f  = __popc(l & (l >> 1) & 0x1F) & 1;  // pairs among qubits 0-5
        int l5 = (l >> 5) & 1, l0 = l & 1;
        float sg0 = f              ? -1.f : 1.f;
        float sg1 = (f ^ l5)       ? -1.f : 1.f;   // e0=1: pair (5,6)
        float sg2 = (f ^ l0)       ? -1.f : 1.f;   // e5=1: pair (0,11)
        float sg3 = (f ^ l5 ^ l0)  ? -1.f : 1.f;
#pragma unroll
        for (int e = 0; e < 64; ++e) {
            const int Ce  = __popc(e & (e >> 1) & 0x1F) & 1;  // pairs among 6-11
            const int sel = (e & 1) | (((e >> 5) & 1) << 1);
            float sgn;
            if      (sel == 0) sgn = sg0;
            else if (sel == 1) sgn = sg1;
            else if (sel == 2) sgn = sg2;
            else               sgn = sg3;
            r[e] *= (Ce ? -sgn : sgn);
        }
    }

    // ---- layer 2 on qubits 6-11 (theta[18..23]) ----
    liftLayer<0>(r, rlane(tt, 18), rlane(ss, 18));
    liftLayer<1>(r, rlane(tt, 19), rlane(ss, 19));
    liftLayer<2>(r, rlane(tt, 20), rlane(ss, 20));
    liftLayer<3>(r, rlane(tt, 21), rlane(ss, 21));
    liftLayer<4>(r, rlane(tt, 22), rlane(ss, 22));
    liftLayer<5>(r, rlane(tt, 23), rlane(ss, 23));

    transpose64(r, lds, l);                  // r[j] = state[l*64 + j]

    // ---- pass 3: qubits 0-5, layer 2 (theta[12..17]) ----
    liftLayer<0>(r, rlane(tt, 12), rlane(ss, 12));
    liftLayer<1>(r, rlane(tt, 13), rlane(ss, 13));
    liftLayer<2>(r, rlane(tt, 14), rlane(ss, 14));
    liftLayer<3>(r, rlane(tt, 15), rlane(ss, 15));
    liftLayer<4>(r, rlane(tt, 16), rlane(ss, 16));
    liftLayer<5>(r, rlane(tt, 17), rlane(ss, 17));

    // ---- measurement (verified): bits 0-5 of d = j, bits 6-9 = l&15 ----
    float psum = 0.f;
#pragma unroll
    for (int j = 0; j < 64; ++j) psum = fmaf(r[j], r[j], psum);

    float v[10];
#pragma unroll
    for (int k = 0; k < 6; ++k) {
        float mk = 0.f;
#pragma unroll
        for (int j = 0; j < 64; ++j)
            if (j & (1 << k)) mk = fmaf(r[j], r[j], mk);
        v[k] = mk;
    }
    v[6] = (l & 1) ? psum : 0.f;
    v[7] = (l & 2) ? psum : 0.f;
    v[8] = (l & 4) ? psum : 0.f;
    v[9] = (l & 8) ? psum : 0.f;

#pragma unroll
    for (int k = 0; k < 10; ++k) {
        float t = v[k];
#pragma unroll
        for (int off = 32; off >= 1; off >>= 1)
            t += __shfl_xor(t, off, 64);
        v[k] = t;
    }

    if (l == 0) {
#pragma unroll
        for (int k = 0; k < KOUT; ++k) out[b * KOUT + k] = v[k];
    }
}

extern "C" void kernel_launch(void* const* d_in, const int* in_sizes, int n_in,
                              void* d_out, int out_size, void* d_ws, size_t ws_size,
                              hipStream_t stream) {
    const float* x     = (const float*)d_in[0];
    const float* theta = (const float*)d_in[1];
    float* out         = (float*)d_out;
    vqc_kernel<<<BATCH, 64, 0, stream>>>(x, theta, out);
}